// Round 13
// baseline (271.179 us; speedup 1.0000x reference)
//
#include <hip/hip_runtime.h>
#include <math.h>

// Problem constants
#define BB 2
#define TT 2048
#define CC 768
#define NH 12
#define HD 64
#define DFF 3072
#define MM (BB*TT)          // 4096 rows

typedef _Float16 f16;
typedef unsigned long long u64;
typedef unsigned int u32;
typedef __attribute__((ext_vector_type(8))) _Float16 f16x8;
typedef __attribute__((ext_vector_type(4))) _Float16 f16x4;
typedef __attribute__((ext_vector_type(4))) float f32x4;
typedef __attribute__((ext_vector_type(2))) unsigned int u32x2;
typedef __attribute__((ext_vector_type(4))) unsigned int u32x4;

// q pre-scale: D^-0.5 * log2(e) so attention scores are ready for exp2
#define QSCALE 0.18033688011112042f

// global -> LDS direct DMA, 16B/lane; LDS dest = wave-uniform base + lane*16
#define GLD_LDS(gptr, lptr) \
  __builtin_amdgcn_global_load_lds((const __attribute__((address_space(1))) void*)(gptr), \
                                   (__attribute__((address_space(3))) void*)(lptr), 16, 0, 0)

#if __has_builtin(__builtin_amdgcn_exp2f)
#define EXP2(x) __builtin_amdgcn_exp2f(x)
#else
#define EXP2(x) exp2f(x)
#endif

#if __has_builtin(__builtin_amdgcn_rcpf)
#define RCP(x) __builtin_amdgcn_rcpf(x)
#else
#define RCP(x) (1.f / (x))
#endif

#if __has_builtin(__builtin_amdgcn_permlane32_swap) && __has_builtin(__builtin_amdgcn_permlane16_swap)
#define HAVE_PERMLANE_SWAP 1
#else
#define HAVE_PERMLANE_SWAP 0
#endif

// pack two f32 -> packed f16 pair in a u32 (round-toward-zero)
__device__ __forceinline__ u32 pkrtz(float a, float b)
{
    auto h = __builtin_amdgcn_cvt_pkrtz(a, b);   // __fp16 ext_vector(2)
    return __builtin_bit_cast(u32, h);
}

// fast exact-GELU: A&S 7.1.26 erf, |eps| <= 1.5e-7
__device__ __forceinline__ float gelu_f(float x)
{
    const float y = fabsf(x) * 0.70710678118654752f;
    const float t = RCP(fmaf(0.3275911f, y, 1.f));
    float p = fmaf(1.061405429f, t, -1.453152027f);
    p = fmaf(p, t, 1.421413741f);
    p = fmaf(p, t, -0.284496736f);
    p = fmaf(p, t, 0.254829592f);
    p = p * t;
    const float e = EXP2(-y * y * 1.4426950408889634f);
    const float er = copysignf(1.f - p * e, x);
    return 0.5f * x * (1.f + er);
}

// ---------------------------------------------------------------------------
// Fused conversions: x->f16 + 4 weight transposes, one launch.
// blocks [0,3072): x | [3072,4800): Wqkv | [4800,5376): Wp
// [5376,7680): W1 | [7680,9984): W2
// ---------------------------------------------------------------------------
__device__ __forceinline__ void transpose_tile(const float* __restrict__ W,
                                               f16* __restrict__ Wt,
                                               int K, int N, int idx,
                                               float tile[32][33])
{
    const int kx = idx % (K / 32), ny = idx / (K / 32);
    const int k0 = kx * 32, n0 = ny * 32;
    const int r  = threadIdx.x >> 3;
    const int c4 = (threadIdx.x & 7) * 4;
    float4 v = *(const float4*)&W[(size_t)(k0 + r) * N + n0 + c4];
    tile[r][c4 + 0] = v.x; tile[r][c4 + 1] = v.y;
    tile[r][c4 + 2] = v.z; tile[r][c4 + 3] = v.w;
    __syncthreads();
    f16x4 o = {(f16)tile[c4 + 0][r], (f16)tile[c4 + 1][r],
               (f16)tile[c4 + 2][r], (f16)tile[c4 + 3][r]};
    *(f16x4*)&Wt[(size_t)(n0 + r) * K + k0 + c4] = o;
}

__global__ __launch_bounds__(256)
void conv_all(const float* __restrict__ x, f16* __restrict__ xh,
              const float* __restrict__ Wqkv, f16* __restrict__ Wqkvt,
              const float* __restrict__ Wp, f16* __restrict__ Wpt,
              const float* __restrict__ W1, f16* __restrict__ W1t,
              const float* __restrict__ W2, f16* __restrict__ W2t)
{
    __shared__ float tile[32][33];
    const int blk = blockIdx.x;
    if (blk < 3072) {
        const int i = blk * 256 + threadIdx.x;
        float4 v = ((const float4*)x)[i];
        f16x4 o = {(f16)v.x, (f16)v.y, (f16)v.z, (f16)v.w};
        ((f16x4*)xh)[i] = o;
    } else if (blk < 4800) {
        transpose_tile(Wqkv, Wqkvt, CC, 3 * CC, blk - 3072, tile);
    } else if (blk < 5376) {
        transpose_tile(Wp, Wpt, CC, CC, blk - 4800, tile);
    } else if (blk < 7680) {
        transpose_tile(W1, W1t, CC, DFF, blk - 5376, tile);
    } else {
        transpose_tile(W2, W2t, DFF, CC, blk - 7680, tile);
    }
}

// ---------------------------------------------------------------------------
// MFMA GEMM: C[M,N] = A[M,K] @ B[K,N] + bias.  A row-major f16, Bt = B^T f16.
// 64 x 128 tile, BK=32, QUAD-buffered LDS with ONE barrier per 2 K-steps
// (verified R10: all four GEMMs out of the top-5; total 280->266.5).
// MINW caps unified VGPR+AGPR (attn-verified mechanism, R6).
// NO setprio here: m190 evidence says it hurts barrier-locked GEMMs.
// AMODE=1 (proj): A-operand is the attention combine
//   A[r,c] = (O0[r,c]+O1[r,c]) / (l0[r,c>>6]+l1[r,c>>6]), reg-staged into As.
// OUT_MODE: 1=f16 row-major; 2=qkv split (q scaled; k/v MFMA-tiled, v masked).
// ---------------------------------------------------------------------------
template<int TM, int OUT_MODE, int GELU, int SPLITK, int AMODE, int MINW>
__global__ __launch_bounds__(256, MINW)
void gemm_mfma(const f16* __restrict__ A, const f16* __restrict__ Bt,
               const float* __restrict__ bias, void* __restrict__ Cout,
               f16* __restrict__ Kout, f16* __restrict__ Vout,
               const int* __restrict__ maskp, int M, int N, int K,
               const f16* __restrict__ Ao1,
               const float* __restrict__ lp0, const float* __restrict__ lp1)
{
    static_assert(TM == 64, "quad-buffer path is TM=64 only");
    constexpr int NT = 2;
    constexpr int G  = 512 / TM;           // A-strips per XCD window (M=4096)
    __shared__ f16 As[4][TM * 32];
    __shared__ f16 Bs[4][128 * 32];

    int id = blockIdx.x;
    int kk = 0;
    if (SPLITK == 2) { kk = id & 1; id >>= 1; }
    const int xcd = id & 7, j = id >> 3;
    const int by = xcd * G + (j & (G - 1));
    const int bx = j / G;
    const int Keff = K / SPLITK;

    const int t = threadIdx.x;
    const int lane = t & 63, w = t >> 6;
    const int fr = lane & 15, quad = lane >> 4;
    const int row0 = by * TM, col0 = bx * 128;
    const int wn = w * 32;

    const int arow = w * (TM / 4) + (lane >> 2);
    const int brow = w * 32 + (lane >> 2);
    const int cg = (((lane & 3) ^ ((lane >> 3) & 3)) * 16);
    const char* ag = (const char*)(A  + (size_t)(row0 + arow) * K + kk * Keff) + cg;
    const char* bg = (const char*)(Bt + (size_t)(col0 + brow) * K + kk * Keff) + cg;
    const size_t rowK = (size_t)K * 2;
    const int wA = w * (TM / 4) * 32;
    const int wB = w * 32 * 32;
    const int sof = (quad ^ ((fr >> 1) & 3)) * 8;

    // AMODE A-combine staging state
    const f16 *a0p = nullptr, *a1p = nullptr;
    const float *lr0 = nullptr, *lr1 = nullptr;
    int lchunk8 = 0, aoff = 0;
    if (AMODE) {
        const int strow = lane >> 2, pchunk = lane & 3;
        lchunk8 = ((pchunk ^ ((lane >> 3) & 3))) * 8;
        const int ar = row0 + w * 16 + strow;
        a0p = A   + (size_t)ar * K + kk * Keff + lchunk8;
        a1p = Ao1 + (size_t)ar * K + kk * Keff + lchunk8;
        lr0 = lp0 + ar * NH;
        lr1 = lp1 + ar * NH;
        aoff = wA + strow * 32 + pchunk * 8;
    }

    f32x4 acc[4][NT] = {};

    // prologue: stage steps 0,1 into bufs 0,1
    if (AMODE) {
#pragma unroll
        for (int s = 0; s < 2; ++s) {
            f16x8 a0 = *(const f16x8*)(a0p + s * 32);
            f16x8 a1 = *(const f16x8*)(a1p + s * 32);
            const int hh = (kk * Keff + s * 32 + lchunk8) >> 6;
            const f16 lh = (f16)RCP(lr0[hh] + lr1[hh]);
            f16x8 sv;
#pragma unroll
            for (int jj = 0; jj < 8; ++jj) sv[jj] = (f16)((a0[jj] + a1[jj]) * lh);
            *(f16x8*)&As[s][aoff] = sv;
        }
    } else {
        GLD_LDS(ag, &As[0][wA]);
        GLD_LDS(ag + 64, &As[1][wA]);
    }
    GLD_LDS(bg, &Bs[0][wB]);
    GLD_LDS(bg + 16 * rowK, &Bs[0][wB + 16 * 32]);
    GLD_LDS(bg + 64, &Bs[1][wB]);
    GLD_LDS(bg + 64 + 16 * rowK, &Bs[1][wB + 16 * 32]);

    for (int k0 = 0; k0 < Keff; k0 += 64) {
        const int b0 = (k0 >> 5) & 3;
        const int b1 = (b0 + 1) & 3;
        // pre-barrier register loads for next superstep's A (AMODE)
        f16x8 na00, na10, na01, na11;
        float nls0 = 1.f, nls1 = 1.f;
        if (AMODE && k0 + 64 < Keff) {
            na00 = *(const f16x8*)(a0p + k0 + 64);
            na10 = *(const f16x8*)(a1p + k0 + 64);
            na01 = *(const f16x8*)(a0p + k0 + 96);
            na11 = *(const f16x8*)(a1p + k0 + 96);
            const int h0 = (kk * Keff + k0 + 64 + lchunk8) >> 6;
            const int h1 = (kk * Keff + k0 + 96 + lchunk8) >> 6;
            nls0 = lr0[h0] + lr1[h0];
            nls1 = lr0[h1] + lr1[h1];
        }
        __syncthreads();   // drains prev superstep's loads (bufs b0,b1 ready)
        if (k0 + 64 < Keff) {    // Keff % 64 == 0 -> both steps exist
            const int b2 = (b0 + 2) & 3, b3 = (b0 + 3) & 3;
            const size_t kb = (size_t)(k0 + 64) * 2;
            if (AMODE) {
                const f16 lh0 = (f16)RCP(nls0);
                f16x8 s0;
#pragma unroll
                for (int jj = 0; jj < 8; ++jj) s0[jj] = (f16)((na00[jj] + na10[jj]) * lh0);
                *(f16x8*)&As[b2][aoff] = s0;
                const f16 lh1 = (f16)RCP(nls1);
                f16x8 s1;
#pragma unroll
                for (int jj = 0; jj < 8; ++jj) s1[jj] = (f16)((na01[jj] + na11[jj]) * lh1);
                *(f16x8*)&As[b3][aoff] = s1;
            } else {
                GLD_LDS(ag + kb, &As[b2][wA]);
                GLD_LDS(ag + kb + 64, &As[b3][wA]);
            }
            GLD_LDS(bg + kb, &Bs[b2][wB]);
            GLD_LDS(bg + kb + 16 * rowK, &Bs[b2][wB + 16 * 32]);
            GLD_LDS(bg + kb + 64, &Bs[b3][wB]);
            GLD_LDS(bg + kb + 64 + 16 * rowK, &Bs[b3][wB + 16 * 32]);
        }
        // compute step k0 (buf b0) then k0+32 (buf b1) — no barrier between
        {
            f16x8 af[4], bf[NT];
#pragma unroll
            for (int mt = 0; mt < 4; ++mt)
                af[mt] = *(const f16x8*)&As[b0][(mt * 16 + fr) * 32 + sof];
#pragma unroll
            for (int nt = 0; nt < NT; ++nt)
                bf[nt] = *(const f16x8*)&Bs[b0][(wn + nt * 16 + fr) * 32 + sof];
#pragma unroll
            for (int mt = 0; mt < 4; ++mt)
#pragma unroll
                for (int nt = 0; nt < NT; ++nt)
                    acc[mt][nt] = __builtin_amdgcn_mfma_f32_16x16x32_f16(
                        af[mt], bf[nt], acc[mt][nt], 0, 0, 0);
        }
        {
            f16x8 af[4], bf[NT];
#pragma unroll
            for (int mt = 0; mt < 4; ++mt)
                af[mt] = *(const f16x8*)&As[b1][(mt * 16 + fr) * 32 + sof];
#pragma unroll
            for (int nt = 0; nt < NT; ++nt)
                bf[nt] = *(const f16x8*)&Bs[b1][(wn + nt * 16 + fr) * 32 + sof];
#pragma unroll
            for (int mt = 0; mt < 4; ++mt)
#pragma unroll
                for (int nt = 0; nt < NT; ++nt)
                    acc[mt][nt] = __builtin_amdgcn_mfma_f32_16x16x32_f16(
                        af[mt], bf[nt], acc[mt][nt], 0, 0, 0);
        }
    }

    // epilogue. C/D layout: col = lane&15, row = quad*4 + v
    float bvs[NT];
#pragma unroll
    for (int nt = 0; nt < NT; ++nt)
        bvs[nt] = (SPLITK == 2 && kk) ? 0.f : bias[col0 + wn + nt * 16 + fr];
    f16* outbase = (f16*)Cout + (SPLITK == 2 ? (size_t)kk * M * N : 0);
#pragma unroll
    for (int mt = 0; mt < 4; ++mt) {
        const int rowb = row0 + mt * 16 + quad * 4;
        float mv[4] = {1.f, 1.f, 1.f, 1.f};
        if (OUT_MODE == 2 && col0 >= 1536) {
            int4 mi = *(const int4*)&maskp[rowb];
            mv[0] = mi.x ? 1.f : 0.f; mv[1] = mi.y ? 1.f : 0.f;
            mv[2] = mi.z ? 1.f : 0.f; mv[3] = mi.w ? 1.f : 0.f;
        }
#pragma unroll
        for (int nt = 0; nt < NT; ++nt) {
            const int col = col0 + wn + nt * 16 + fr;
            if (OUT_MODE == 2) {
                const int bq = rowb >> 11, sb = rowb & 2047;
                if (col0 < 768) {                        // q -> Qout (scaled)
#pragma unroll
                    for (int v = 0; v < 4; ++v)
                        ((f16*)Cout)[(size_t)(rowb + v) * 768 + col]
                            = (f16)((acc[mt][nt][v] + bvs[nt]) * QSCALE);
                } else if (col0 < 1536) {                // k -> Kout tiles
                    const int dg = col - 768;
                    const int hh = dg >> 6, dd = dg & 63;
                    f16* kb = Kout + (size_t)(bq * NH + hh) * (TT * HD);
#pragma unroll
                    for (int v = 0; v < 4; ++v) {
                        const int s = sb + v;
                        kb[((s >> 4) * 128 + (dd >> 3) * 16 + (s & 15)) * 8 + (dd & 7)]
                            = (f16)(acc[mt][nt][v] + bvs[nt]);
                    }
                } else {                                 // v -> Vout tiles (masked)
                    const int dg = col - 1536;
                    const int hh = dg >> 6, dd = dg & 63;
                    f16* vb = Vout + (size_t)(bq * NH + hh) * (TT * HD);
                    f16x4 pk = {(f16)((acc[mt][nt][0] + bvs[nt]) * mv[0]),
                                (f16)((acc[mt][nt][1] + bvs[nt]) * mv[1]),
                                (f16)((acc[mt][nt][2] + bvs[nt]) * mv[2]),
                                (f16)((acc[mt][nt][3] + bvs[nt]) * mv[3])};
                    *(f16x4*)&vb[((sb >> 3) * 64 + dd) * 8 + (sb & 7)] = pk;
                }
            } else {
#pragma unroll
                for (int v = 0; v < 4; ++v) {
                    float o = acc[mt][nt][v] + bvs[nt];
                    if (GELU) o = gelu_f(o);
                    outbase[(size_t)(rowb + v) * N + col] = (f16)o;
                }
            }
        }
    }
}

// ---------------------------------------------------------------------------
// Barrier-free MFMA flash attention, key-range SPLIT (shalf in {0,1}).
// __launch_bounds__(256,3): verified R6 (-7us); R11 showed 4 regresses.
// s_setprio around MFMA clusters (T5, R12: small consistent win).
// 2-DEEP PING-PONG (R13): QK^T of tile t+1 is issued BEFORE softmax of tile
// t, so the softmax VALU chain executes under the MFMA pipe's shadow
// (separate pipes, m114). Explicit A/B state names — no runtime-indexed
// arrays (rule #20), no rotate movs. Final half-iteration issues one
// past-the-end K load + QK whose result is discarded (reads stay inside the
// allocated kth/vth workspace — same pattern as the R1-verified prefetch).
// ---------------------------------------------------------------------------
__global__ __launch_bounds__(256, 3)
void attn_mfma(const f16* __restrict__ qh, const f16* __restrict__ kth,
               const f16* __restrict__ vth, const int* __restrict__ mask,
               f16* __restrict__ O0, f16* __restrict__ O1,
               float* __restrict__ l0, float* __restrict__ l1)
{
    __shared__ __align__(16) char smem[16640];
    f16* Mf = (f16*)smem;                  // [2048] f16 mask row, 4KB
#if !HAVE_PERMLANE_SWAP
    f16* Ps = (f16*)(smem + 4096);         // [64][72] 9216B (fallback only)
#endif
    float* Ored  = (float*)smem;           // [64][64] f32 16KB (end only, overlays)
    float* lredp = (float*)(smem + 16384); // [64] f32

    const int id = blockIdx.x;
    const int xcd = id & 7, j = id >> 3;          // j in 0..191
    const int pair = xcd * 3 + j % 3;             // 0..23 = b*NH + h
    const int rem = j / 3;                        // 0..63
    const int qt = rem >> 1, shalf = rem & 1;
    const int b = pair / NH, h = pair % NH;

    const int t = threadIdx.x, lane = t & 63, w = t >> 6;
    const int wq = w >> 1, ws = w & 1;
    const int fr = lane & 15, quad = lane >> 4;

    // mask ints -> f16 row in LDS
    {
        int4 mi0 = *(const int4*)&mask[b * TT + t * 8];
        int4 mi1 = *(const int4*)&mask[b * TT + t * 8 + 4];
        f16x8 mrow;
        mrow[0] = mi0.x ? (f16)1.f : (f16)0.f; mrow[1] = mi0.y ? (f16)1.f : (f16)0.f;
        mrow[2] = mi0.z ? (f16)1.f : (f16)0.f; mrow[3] = mi0.w ? (f16)1.f : (f16)0.f;
        mrow[4] = mi1.x ? (f16)1.f : (f16)0.f; mrow[5] = mi1.y ? (f16)1.f : (f16)0.f;
        mrow[6] = mi1.z ? (f16)1.f : (f16)0.f; mrow[7] = mi1.w ? (f16)1.f : (f16)0.f;
        *(f16x8*)&Mf[t * 8] = mrow;
    }

    // Q B-frags direct from global: B[k=d][n=q], lane fr = q
    f16x8 qf[2][2];
#pragma unroll
    for (int nt = 0; nt < 2; ++nt)
#pragma unroll
        for (int ks = 0; ks < 2; ++ks)
            qf[nt][ks] = *(const f16x8*)&qh[(size_t)(b * TT + qt * 64 + wq * 32 + nt * 16 + fr) * CC
                                            + h * HD + ks * 32 + quad * 8];

    __syncthreads();   // Mf visible

    const f16* KB = kth + (size_t)(b * NH + h) * (TT * HD);
    const f16* VB = vth + (size_t)(b * NH + h) * (TT * HD);
    int ko[2][2], vo[4];
#pragma unroll
    for (int mt = 0; mt < 2; ++mt)
#pragma unroll
        for (int ks = 0; ks < 2; ++ks)
            ko[mt][ks] = ((ws * 2 + mt) * 128 + (ks * 4 + quad) * 16 + fr) * 8;
#pragma unroll
    for (int nt = 0; nt < 4; ++nt)
        vo[nt] = ((ws * 4 + quad) * 64 + nt * 16 + fr) * 8;

    f32x4 oacc[2][4] = {};
    f32x4 lacc[2] = {};

    const int it0 = shalf * 16;

#if HAVE_PERMLANE_SWAP
    // softmax+PV for one tile from sacc/vf/mf (verbatim per-tile math)
#define SOFTMAX_PV(SACC, VF, MF)                                              \
    {                                                                         \
        _Pragma("unroll")                                                     \
        for (int nt = 0; nt < 2; ++nt) {                                      \
            const u32 pa = pkrtz(EXP2(SACC[0][nt][0]), EXP2(SACC[0][nt][1])); \
            const u32 pb = pkrtz(EXP2(SACC[0][nt][2]), EXP2(SACC[0][nt][3])); \
            const u32 pc = pkrtz(EXP2(SACC[1][nt][0]), EXP2(SACC[1][nt][1])); \
            const u32 pd = pkrtz(EXP2(SACC[1][nt][2]), EXP2(SACC[1][nt][3])); \
            const u32x2 e0 = __builtin_amdgcn_permlane32_swap(pa, pc, false, false); \
            const u32x2 e1 = __builtin_amdgcn_permlane16_swap(e0.x, e0.y, false, false); \
            const u32x2 e2 = __builtin_amdgcn_permlane32_swap(pb, pd, false, false); \
            const u32x2 e3 = __builtin_amdgcn_permlane16_swap(e2.x, e2.y, false, false); \
            const u32x4 pw = {e1.x, e3.x, e1.y, e3.y};                        \
            const f16x8 pfr = __builtin_bit_cast(f16x8, pw);                  \
            __builtin_amdgcn_s_setprio(1);                                    \
            lacc[nt] = __builtin_amdgcn_mfma_f32_16x16x32_f16(pfr, MF, lacc[nt], 0, 0, 0); \
            _Pragma("unroll")                                                 \
            for (int vt = 0; vt < 4; ++vt)                                    \
                oacc[nt][vt] = __builtin_amdgcn_mfma_f32_16x16x32_f16(        \
                    pfr, VF[vt], oacc[nt][vt], 0, 0, 0);                      \
            __builtin_amdgcn_s_setprio(0);                                    \
        }                                                                     \
    }

    // prologue: K(it0) + QK(it0) -> state A
    f16x8 kfA[2][2];
#pragma unroll
    for (int mt = 0; mt < 2; ++mt)
#pragma unroll
        for (int ks = 0; ks < 2; ++ks)
            kfA[mt][ks] = *(const f16x8*)(KB + it0 * 4096 + ko[mt][ks]);
    f32x4 saccA[2][2] = {};
    __builtin_amdgcn_s_setprio(1);
#pragma unroll
    for (int mt = 0; mt < 2; ++mt)
#pragma unroll
        for (int nt = 0; nt < 2; ++nt) {
            saccA[mt][nt] = __builtin_amdgcn_mfma_f32_16x16x32_f16(
                kfA[mt][0], qf[nt][0], saccA[mt][nt], 0, 0, 0);
            saccA[mt][nt] = __builtin_amdgcn_mfma_f32_16x16x32_f16(
                kfA[mt][1], qf[nt][1], saccA[mt][nt], 0, 0, 0);
        }
    __builtin_amdgcn_s_setprio(0);

    for (int it = it0; it < it0 + 16; it += 2) {
        const int ibA = it * 4096, ibB = ibA + 4096, ibC = ibB + 4096;
        // ---- half 1: prefetch+QK tile it+1 (B), then softmax+PV tile it (A)
        f16x8 vfA[4];
#pragma unroll
        for (int nt = 0; nt < 4; ++nt)
            vfA[nt] = *(const f16x8*)(VB + ibA + vo[nt]);
        f16x8 kfB[2][2];
#pragma unroll
        for (int mt = 0; mt < 2; ++mt)
#pragma unroll
            for (int ks = 0; ks < 2; ++ks)
                kfB[mt][ks] = *(const f16x8*)(KB + ibB + ko[mt][ks]);
        f32x4 saccB[2][2] = {};
        __builtin_amdgcn_s_setprio(1);
#pragma unroll
        for (int mt = 0; mt < 2; ++mt)
#pragma unroll
            for (int nt = 0; nt < 2; ++nt) {
                saccB[mt][nt] = __builtin_amdgcn_mfma_f32_16x16x32_f16(
                    kfB[mt][0], qf[nt][0], saccB[mt][nt], 0, 0, 0);
                saccB[mt][nt] = __builtin_amdgcn_mfma_f32_16x16x32_f16(
                    kfB[mt][1], qf[nt][1], saccB[mt][nt], 0, 0, 0);
            }
        __builtin_amdgcn_s_setprio(0);
        const f16x8 mfA = *(const f16x8*)&Mf[it * 64 + ws * 32 + quad * 8];
        SOFTMAX_PV(saccA, vfA, mfA)

        // ---- half 2: prefetch+QK tile it+2 (A', may be one past end —
        // reads stay in allocated ws; result discarded), then softmax+PV B
        f16x8 vfB[4];
#pragma unroll
        for (int nt = 0; nt < 4; ++nt)
            vfB[nt] = *(const f16x8*)(VB + ibB + vo[nt]);
#pragma unroll
        for (int mt = 0; mt < 2; ++mt)
#pragma unroll
            for (int ks = 0; ks < 2; ++ks)
                kfA[mt][ks] = *(const f16x8*)(KB + ibC + ko[mt][ks]);
#pragma unroll
        for (int mt = 0; mt < 2; ++mt)
#pragma unroll
            for (int nt = 0; nt < 2; ++nt)
                saccA[mt][nt] = f32x4{0.f, 0.f, 0.f, 0.f};
        __builtin_amdgcn_s_setprio(1);
#pragma unroll
        for (int mt = 0; mt < 2; ++mt)
#pragma unroll
            for (int nt = 0; nt < 2; ++nt) {
                saccA[mt][nt] = __builtin_amdgcn_mfma_f32_16x16x32_f16(
                    kfA[mt][0], qf[nt][0], saccA[mt][nt], 0, 0, 0);
                saccA[mt][nt] = __builtin_amdgcn_mfma_f32_16x16x32_f16(
                    kfA[mt][1], qf[nt][1], saccA[mt][nt], 0, 0, 0);
            }
        __builtin_amdgcn_s_setprio(0);
        const f16x8 mfB = *(const f16x8*)&Mf[(it + 1) * 64 + ws * 32 + quad * 8];
        SOFTMAX_PV(saccB, vfB, mfB)
    }
#undef SOFTMAX_PV
#else
    // fallback: original single-tile loop with LDS round trip
#pragma unroll 2
    for (int it = it0; it < it0 + 16; ++it) {
        const int ib = it * 4096;
        f16x8 vf[4];
#pragma unroll
        for (int nt = 0; nt < 4; ++nt)
            vf[nt] = *(const f16x8*)(VB + ib + vo[nt]);
        f16x8 kf[2][2];
#pragma unroll
        for (int mt = 0; mt < 2; ++mt)
#pragma unroll
            for (int ks = 0; ks < 2; ++ks)
                kf[mt][ks] = *(const f16x8*)(KB + ib + ko[mt][ks]);

        f32x4 sacc[2][2] = {};
#pragma unroll
        for (int mt = 0; mt < 2; ++mt)
#pragma unroll
            for (int nt = 0; nt < 2; ++nt) {
                sacc[mt][nt] = __builtin_amdgcn_mfma_f32_16x16x32_f16(
                    kf[mt][0], qf[nt][0], sacc[mt][nt], 0, 0, 0);
                sacc[mt][nt] = __builtin_amdgcn_mfma_f32_16x16x32_f16(
                    kf[mt][1], qf[nt][1], sacc[mt][nt], 0, 0, 0);
            }

        f16x8 mf = *(const f16x8*)&Mf[it * 64 + ws * 32 + quad * 8];
#pragma unroll
        for (int mt = 0; mt < 2; ++mt)
#pragma unroll
            for (int nt = 0; nt < 2; ++nt) {
                f16x4 pk = {(f16)EXP2(sacc[mt][nt][0]), (f16)EXP2(sacc[mt][nt][1]),
                            (f16)EXP2(sacc[mt][nt][2]), (f16)EXP2(sacc[mt][nt][3])};
                *(f16x4*)&Ps[(wq * 32 + nt * 16 + fr) * 72 + ws * 32 + mt * 16 + quad * 4] = pk;
            }
        f16x8 pf[2];
#pragma unroll
        for (int mt = 0; mt < 2; ++mt)
            pf[mt] = *(const f16x8*)&Ps[(wq * 32 + mt * 16 + fr) * 72 + ws * 32 + quad * 8];
#pragma unroll
        for (int mt = 0; mt < 2; ++mt) {
            lacc[mt] = __builtin_amdgcn_mfma_f32_16x16x32_f16(pf[mt], mf, lacc[mt], 0, 0, 0);
#pragma unroll
            for (int nt = 0; nt < 4; ++nt)
                oacc[mt][nt] = __builtin_amdgcn_mfma_f32_16x16x32_f16(
                    pf[mt], vf[nt], oacc[mt][nt], 0, 0, 0);
        }
    }
#endif

    // cross-(ws) reduction; write unnormalized partials
    f16* Oout = shalf ? O1 : O0;
    float* lout = shalf ? l1 : l0;
    __syncthreads();
    if (ws == 1) {
#pragma unroll
        for (int mt = 0; mt < 2; ++mt) {
            const int q = wq * 32 + mt * 16 + quad * 4;
#pragma unroll
            for (int nt = 0; nt < 4; ++nt)
#pragma unroll
                for (int v = 0; v < 4; ++v)
                    Ored[(q + v) * 64 + nt * 16 + fr] = oacc[mt][nt][v];
            if (fr == 0)
#pragma unroll
                for (int v = 0; v < 4; ++v) lredp[q + v] = lacc[mt][v];
        }
    }
    __syncthreads();
    if (ws == 0) {
#pragma unroll
        for (int mt = 0; mt < 2; ++mt) {
            const int q0 = wq * 32 + mt * 16 + quad * 4;
            if (fr == 0)
#pragma unroll
                for (int v = 0; v < 4; ++v)
                    lout[(size_t)(b * TT + qt * 64 + q0 + v) * NH + h]
                        = lacc[mt][v] + lredp[q0 + v];
#pragma unroll
            for (int nt = 0; nt < 4; ++nt)
#pragma unroll
                for (int v = 0; v < 4; ++v) {
                    float o = oacc[mt][nt][v] + Ored[(q0 + v) * 64 + nt * 16 + fr];
                    Oout[(size_t)(b * TT + qt * 64 + q0 + v) * CC + h * HD + nt * 16 + fr]
                        = (f16)o;
                }
        }
    }
}

// ---------------------------------------------------------------------------
// out = res + LN(y0+y1)*gamma + beta, 8 rows/block, vectorized.
// ---------------------------------------------------------------------------
template<int WRITE_H>
__global__ __launch_bounds__(256)
void ln_residual(const float* __restrict__ res,
                 const f16* __restrict__ y0, const f16* __restrict__ y1,
                 const float* __restrict__ gamma, const float* __restrict__ beta,
                 float* __restrict__ outp, f16* __restrict__ outh)
{
    const int t = threadIdx.x;
    const int row = blockIdx.x * 8 + (t >> 5);
    const int c0 = (t & 31) * 24;
    const f16* yr0 = y0 + (size_t)row * CC + c0;
    const f16* yr1 = y1 + (size_t)row * CC + c0;
    float v[24];
    float s = 0.f, sq = 0.f;
#pragma unroll
    for (int i = 0; i < 3; ++i) {
        f16x8 a = *(const f16x8*)(yr0 + i * 8);
        f16x8 bb = *(const f16x8*)(yr1 + i * 8);
#pragma unroll
        for (int jj = 0; jj < 8; ++jj) {
            float vv = (float)a[jj] + (float)bb[jj];
            v[i * 8 + jj] = vv; s += vv; sq += vv * vv;
        }
    }
#pragma unroll
    for (int off = 1; off < 32; off <<= 1) {
        s  += __shfl_xor(s, off);
        sq += __shfl_xor(sq, off);
    }
    const float mean = s * (1.f / 768.f);
    const float var  = sq * (1.f / 768.f) - mean * mean;
    const float rstd = rsqrtf(var + 1e-5f);
    const float* rr = res + (size_t)row * CC + c0;
    float* orow = outp + (size_t)row * CC + c0;
#pragma unroll
    for (int i = 0; i < 6; ++i) {
        float4 r4 = *(const float4*)(rr + i * 4);
        float4 g4 = *(const float4*)(gamma + c0 + i * 4);
        float4 b4 = *(const float4*)(beta + c0 + i * 4);
        float4 o;
        o.x = r4.x + (v[i*4+0] - mean) * rstd * g4.x + b4.x;
        o.y = r4.y + (v[i*4+1] - mean) * rstd * g4.y + b4.y;
        o.z = r4.z + (v[i*4+2] - mean) * rstd * g4.z + b4.z;
        o.w = r4.w + (v[i*4+3] - mean) * rstd * g4.w + b4.w;
        *(float4*)(orow + i * 4) = o;
        if (WRITE_H) {
            f16x4 h4 = {(f16)o.x, (f16)o.y, (f16)o.z, (f16)o.w};
            *(f16x4*)(outh + (size_t)row * CC + c0 + i * 4) = h4;
        }
    }
}

// ---------------------------------------------------------------------------
extern "C" void kernel_launch(void* const* d_in, const int* in_sizes, int n_in,
                              void* d_out, int out_size, void* d_ws, size_t ws_size,
                              hipStream_t stream)
{
    const float* x     = (const float*)d_in[0];
    const int*   mask  = (const int*)  d_in[1];
    const float* Wqkv  = (const float*)d_in[2];
    const float* bqkv  = (const float*)d_in[3];
    const float* Wp    = (const float*)d_in[4];
    const float* bp    = (const float*)d_in[5];
    const float* g1    = (const float*)d_in[6];
    const float* be1   = (const float*)d_in[7];
    const float* W1    = (const float*)d_in[8];
    const float* b1    = (const float*)d_in[9];
    const float* W2    = (const float*)d_in[10];
    const float* b2    = (const float*)d_in[11];
    const float* g2    = (const float*)d_in[12];
    const float* be2   = (const float*)d_in[13];
    float* outp = (float*)d_out;

    // byte-offset workspace plan (~66.5 MB, overlays by lifetime):
    char* wsb = (char*)d_ws;
    f16*   qhb    = (f16*)(wsb);                 // 6.29MB   gemm1->attn
    f16*   kth    = (f16*)(wsb + 6291456);       // 6.29MB   gemm1->attn
    f16*   vth    = (f16*)(wsb + 12582912);      // 6.29MB   gemm1->attn
    f16*   O0     = (f16*)(wsb + 18874368);      // 6.29MB   attn->gemm3
    f16*   O1     = (f16*)(wsb + 25165824);      // 6.29MB   attn->gemm3 (over xh)
    f16*   hbuf   = (f16*)(wsb);                 // 25.17MB  gemm5->gemm6 (overlay)
    f16*   xh     = (f16*)(wsb + 25165824);      // 6.29MB   conv->gemm1 (then O1)
    float* out1f  = (float*)(wsb + 25165824);    // 12.58MB  ln1->ln2 (over O1/Wqkvt/Wpt)
    f16*   Wqkvt  = (f16*)(wsb + 31457280);      // 3.54MB   ->gemm1
    f16*   Wpt    = (f16*)(wsb + 34996224);      // 1.18MB   ->gemm3
    f16*   W1t    = (f16*)(wsb + 37748736);      // 4.72MB   ->gemm5
    f16*   W2t    = (f16*)(wsb + 42467328);      // 4.72MB   ->gemm6
    f16*   p0     = (f16*)(wsb + 47185920);      // 6.29MB   splitK partial 0
    f16*   p1     = (f16*)(wsb + 53477376);      // 6.29MB   splitK partial 1
    f16*   out1h  = (f16*)(wsb + 59768832);      // 6.29MB   ln1->gemm5
    float* l0     = (float*)(wsb + 66060288);    // 196KB    attn->gemm3
    float* l1     = (float*)(wsb + 66256896);    // 196KB    attn->gemm3; end 66.45MB

    const dim3 blk(256);

    // fused conversions (x + 4 weight transposes)
    conv_all<<<dim3(9984), blk, 0, stream>>>(x, xh, Wqkv, Wqkvt, Wp, Wpt,
                                             W1, W1t, W2, W2t);

    // 1. qkv = x @ Wqkv + bqkv -> qh (scaled) + kth/vth MFMA-tiled (v masked)
    //    48KB LDS -> 3 blocks/CU; MINW=3
    gemm_mfma<64, 2, 0, 1, 0, 3><<<dim3((3 * CC / 128) * (MM / 64)), blk, 0, stream>>>(
        xh, Wqkvt, bqkv, qhb, kth, vth, mask, MM, 3 * CC, CC,
        nullptr, nullptr, nullptr);
    // 2. attention -> unnormalized partials O0/O1 + l0/l1 (s-split, 1536 blocks)
    attn_mfma<<<dim3((TT / 64) * NH * BB * 2), blk, 0, stream>>>(
        qhb, kth, vth, mask, O0, O1, l0, l1);
    // 3. proj = [(O0+O1)/l] @ Wp + bp -> p0+p1 (split-K=2, combine in A-staging)
    gemm_mfma<64, 1, 0, 2, 1, 3><<<dim3(2 * (CC / 128) * (MM / 64)), blk, 0, stream>>>(
        O0, Wpt, bp, p0, nullptr, nullptr, nullptr, MM, CC, CC,
        O1, l0, l1);
    // 4. out1 = x + LN(p0+p1)  (fp32 + f16 copy)
    ln_residual<1><<<dim3(MM / 8), blk, 0, stream>>>(x, p0, p1, g1, be1, out1f, out1h);
    // 5. h = gelu(out1 @ W1 + b1) -> hbuf f16 (quad-buffer, 1 barrier/2 steps)
    gemm_mfma<64, 1, 1, 1, 0, 3><<<dim3((DFF / 128) * (MM / 64)), blk, 0, stream>>>(
        out1h, W1t, b1, hbuf, nullptr, nullptr, nullptr, MM, DFF, CC,
        nullptr, nullptr, nullptr);
    // 6. mlp = h @ W2 + b2 -> p0+p1 (split-K=2)
    gemm_mfma<64, 1, 0, 2, 0, 3><<<dim3(2 * (CC / 128) * (MM / 64)), blk, 0, stream>>>(
        hbuf, W2t, b2, p0, nullptr, nullptr, nullptr, MM, CC, DFF,
        nullptr, nullptr, nullptr);
    // 7. out = out1 + LN(p0+p1)
    ln_residual<0><<<dim3(MM / 8), blk, 0, stream>>>(out1f, p0, p1, g2, be2, outp, nullptr);
}

// Round 14
// 265.852 us; speedup vs baseline: 1.0200x; 1.0200x over previous
//
#include <hip/hip_runtime.h>
#include <math.h>

// Problem constants
#define BB 2
#define TT 2048
#define CC 768
#define NH 12
#define HD 64
#define DFF 3072
#define MM (BB*TT)          // 4096 rows

typedef _Float16 f16;
typedef unsigned long long u64;
typedef unsigned int u32;
typedef __attribute__((ext_vector_type(8))) _Float16 f16x8;
typedef __attribute__((ext_vector_type(4))) _Float16 f16x4;
typedef __attribute__((ext_vector_type(4))) float f32x4;
typedef __attribute__((ext_vector_type(2))) unsigned int u32x2;
typedef __attribute__((ext_vector_type(4))) unsigned int u32x4;

// q pre-scale: D^-0.5 * log2(e) so attention scores are ready for exp2
#define QSCALE 0.18033688011112042f

// global -> LDS direct DMA, 16B/lane; LDS dest = wave-uniform base + lane*16
#define GLD_LDS(gptr, lptr) \
  __builtin_amdgcn_global_load_lds((const __attribute__((address_space(1))) void*)(gptr), \
                                   (__attribute__((address_space(3))) void*)(lptr), 16, 0, 0)

#if __has_builtin(__builtin_amdgcn_exp2f)
#define EXP2(x) __builtin_amdgcn_exp2f(x)
#else
#define EXP2(x) exp2f(x)
#endif

#if __has_builtin(__builtin_amdgcn_rcpf)
#define RCP(x) __builtin_amdgcn_rcpf(x)
#else
#define RCP(x) (1.f / (x))
#endif

#if __has_builtin(__builtin_amdgcn_permlane32_swap) && __has_builtin(__builtin_amdgcn_permlane16_swap)
#define HAVE_PERMLANE_SWAP 1
#else
#define HAVE_PERMLANE_SWAP 0
#endif

// pack two f32 -> packed f16 pair in a u32 (round-toward-zero)
__device__ __forceinline__ u32 pkrtz(float a, float b)
{
    auto h = __builtin_amdgcn_cvt_pkrtz(a, b);   // __fp16 ext_vector(2)
    return __builtin_bit_cast(u32, h);
}

// fast exact-GELU: A&S 7.1.26 erf, |eps| <= 1.5e-7
__device__ __forceinline__ float gelu_f(float x)
{
    const float y = fabsf(x) * 0.70710678118654752f;
    const float t = RCP(fmaf(0.3275911f, y, 1.f));
    float p = fmaf(1.061405429f, t, -1.453152027f);
    p = fmaf(p, t, 1.421413741f);
    p = fmaf(p, t, -0.284496736f);
    p = fmaf(p, t, 0.254829592f);
    p = p * t;
    const float e = EXP2(-y * y * 1.4426950408889634f);
    const float er = copysignf(1.f - p * e, x);
    return 0.5f * x * (1.f + er);
}

// ---------------------------------------------------------------------------
// Fused conversions: x->f16 + 4 weight transposes, one launch.
// blocks [0,3072): x | [3072,4800): Wqkv | [4800,5376): Wp
// [5376,7680): W1 | [7680,9984): W2
// ---------------------------------------------------------------------------
__device__ __forceinline__ void transpose_tile(const float* __restrict__ W,
                                               f16* __restrict__ Wt,
                                               int K, int N, int idx,
                                               float tile[32][33])
{
    const int kx = idx % (K / 32), ny = idx / (K / 32);
    const int k0 = kx * 32, n0 = ny * 32;
    const int r  = threadIdx.x >> 3;
    const int c4 = (threadIdx.x & 7) * 4;
    float4 v = *(const float4*)&W[(size_t)(k0 + r) * N + n0 + c4];
    tile[r][c4 + 0] = v.x; tile[r][c4 + 1] = v.y;
    tile[r][c4 + 2] = v.z; tile[r][c4 + 3] = v.w;
    __syncthreads();
    f16x4 o = {(f16)tile[c4 + 0][r], (f16)tile[c4 + 1][r],
               (f16)tile[c4 + 2][r], (f16)tile[c4 + 3][r]};
    *(f16x4*)&Wt[(size_t)(n0 + r) * K + k0 + c4] = o;
}

__global__ __launch_bounds__(256)
void conv_all(const float* __restrict__ x, f16* __restrict__ xh,
              const float* __restrict__ Wqkv, f16* __restrict__ Wqkvt,
              const float* __restrict__ Wp, f16* __restrict__ Wpt,
              const float* __restrict__ W1, f16* __restrict__ W1t,
              const float* __restrict__ W2, f16* __restrict__ W2t)
{
    __shared__ float tile[32][33];
    const int blk = blockIdx.x;
    if (blk < 3072) {
        const int i = blk * 256 + threadIdx.x;
        float4 v = ((const float4*)x)[i];
        f16x4 o = {(f16)v.x, (f16)v.y, (f16)v.z, (f16)v.w};
        ((f16x4*)xh)[i] = o;
    } else if (blk < 4800) {
        transpose_tile(Wqkv, Wqkvt, CC, 3 * CC, blk - 3072, tile);
    } else if (blk < 5376) {
        transpose_tile(Wp, Wpt, CC, CC, blk - 4800, tile);
    } else if (blk < 7680) {
        transpose_tile(W1, W1t, CC, DFF, blk - 5376, tile);
    } else {
        transpose_tile(W2, W2t, DFF, CC, blk - 7680, tile);
    }
}

// ---------------------------------------------------------------------------
// MFMA GEMM: C[M,N] = A[M,K] @ B[K,N] + bias.  A row-major f16, Bt = B^T f16.
// 64 x 128 tile, BK=32, QUAD-buffered LDS with ONE barrier per 2 K-steps:
// R9 showed occupancy has no marginal value for this kernel — the stall is
// the per-step vmcnt(0)-drain+barrier. Buffers cycle mod 4; each superstep
// stages steps t+2,t+3 (never touching bufs being read, distance-2) and
// computes steps t,t+1 (16 MFMA/wave per barrier instead of 8).
// Verified R10: all four GEMMs dropped out of the top-5 (total 280->266.5).
// MINW caps unified VGPR+AGPR (attn-verified mechanism, R6).
// NO setprio here: m190 evidence says it hurts barrier-locked GEMMs.
// AMODE=1 (proj): A-operand is the attention combine
//   A[r,c] = (O0[r,c]+O1[r,c]) / (l0[r,c>>6]+l1[r,c>>6]), reg-staged into As.
// OUT_MODE: 1=f16 row-major; 2=qkv split (q scaled; k/v MFMA-tiled, v masked).
// ---------------------------------------------------------------------------
template<int TM, int OUT_MODE, int GELU, int SPLITK, int AMODE, int MINW>
__global__ __launch_bounds__(256, MINW)
void gemm_mfma(const f16* __restrict__ A, const f16* __restrict__ Bt,
               const float* __restrict__ bias, void* __restrict__ Cout,
               f16* __restrict__ Kout, f16* __restrict__ Vout,
               const int* __restrict__ maskp, int M, int N, int K,
               const f16* __restrict__ Ao1,
               const float* __restrict__ lp0, const float* __restrict__ lp1)
{
    static_assert(TM == 64, "quad-buffer path is TM=64 only");
    constexpr int NT = 2;
    constexpr int G  = 512 / TM;           // A-strips per XCD window (M=4096)
    __shared__ f16 As[4][TM * 32];
    __shared__ f16 Bs[4][128 * 32];

    int id = blockIdx.x;
    int kk = 0;
    if (SPLITK == 2) { kk = id & 1; id >>= 1; }
    const int xcd = id & 7, j = id >> 3;
    const int by = xcd * G + (j & (G - 1));
    const int bx = j / G;
    const int Keff = K / SPLITK;

    const int t = threadIdx.x;
    const int lane = t & 63, w = t >> 6;
    const int fr = lane & 15, quad = lane >> 4;
    const int row0 = by * TM, col0 = bx * 128;
    const int wn = w * 32;

    const int arow = w * (TM / 4) + (lane >> 2);
    const int brow = w * 32 + (lane >> 2);
    const int cg = (((lane & 3) ^ ((lane >> 3) & 3)) * 16);
    const char* ag = (const char*)(A  + (size_t)(row0 + arow) * K + kk * Keff) + cg;
    const char* bg = (const char*)(Bt + (size_t)(col0 + brow) * K + kk * Keff) + cg;
    const size_t rowK = (size_t)K * 2;
    const int wA = w * (TM / 4) * 32;
    const int wB = w * 32 * 32;
    const int sof = (quad ^ ((fr >> 1) & 3)) * 8;

    // AMODE A-combine staging state
    const f16 *a0p = nullptr, *a1p = nullptr;
    const float *lr0 = nullptr, *lr1 = nullptr;
    int lchunk8 = 0, aoff = 0;
    if (AMODE) {
        const int strow = lane >> 2, pchunk = lane & 3;
        lchunk8 = ((pchunk ^ ((lane >> 3) & 3))) * 8;
        const int ar = row0 + w * 16 + strow;
        a0p = A   + (size_t)ar * K + kk * Keff + lchunk8;
        a1p = Ao1 + (size_t)ar * K + kk * Keff + lchunk8;
        lr0 = lp0 + ar * NH;
        lr1 = lp1 + ar * NH;
        aoff = wA + strow * 32 + pchunk * 8;
    }

    f32x4 acc[4][NT] = {};

    // prologue: stage steps 0,1 into bufs 0,1
    if (AMODE) {
#pragma unroll
        for (int s = 0; s < 2; ++s) {
            f16x8 a0 = *(const f16x8*)(a0p + s * 32);
            f16x8 a1 = *(const f16x8*)(a1p + s * 32);
            const int hh = (kk * Keff + s * 32 + lchunk8) >> 6;
            const f16 lh = (f16)RCP(lr0[hh] + lr1[hh]);
            f16x8 sv;
#pragma unroll
            for (int jj = 0; jj < 8; ++jj) sv[jj] = (f16)((a0[jj] + a1[jj]) * lh);
            *(f16x8*)&As[s][aoff] = sv;
        }
    } else {
        GLD_LDS(ag, &As[0][wA]);
        GLD_LDS(ag + 64, &As[1][wA]);
    }
    GLD_LDS(bg, &Bs[0][wB]);
    GLD_LDS(bg + 16 * rowK, &Bs[0][wB + 16 * 32]);
    GLD_LDS(bg + 64, &Bs[1][wB]);
    GLD_LDS(bg + 64 + 16 * rowK, &Bs[1][wB + 16 * 32]);

    for (int k0 = 0; k0 < Keff; k0 += 64) {
        const int b0 = (k0 >> 5) & 3;
        const int b1 = (b0 + 1) & 3;
        // pre-barrier register loads for next superstep's A (AMODE)
        f16x8 na00, na10, na01, na11;
        float nls0 = 1.f, nls1 = 1.f;
        if (AMODE && k0 + 64 < Keff) {
            na00 = *(const f16x8*)(a0p + k0 + 64);
            na10 = *(const f16x8*)(a1p + k0 + 64);
            na01 = *(const f16x8*)(a0p + k0 + 96);
            na11 = *(const f16x8*)(a1p + k0 + 96);
            const int h0 = (kk * Keff + k0 + 64 + lchunk8) >> 6;
            const int h1 = (kk * Keff + k0 + 96 + lchunk8) >> 6;
            nls0 = lr0[h0] + lr1[h0];
            nls1 = lr0[h1] + lr1[h1];
        }
        __syncthreads();   // drains prev superstep's loads (bufs b0,b1 ready)
        if (k0 + 64 < Keff) {    // Keff % 64 == 0 -> both steps exist
            const int b2 = (b0 + 2) & 3, b3 = (b0 + 3) & 3;
            const size_t kb = (size_t)(k0 + 64) * 2;
            if (AMODE) {
                const f16 lh0 = (f16)RCP(nls0);
                f16x8 s0;
#pragma unroll
                for (int jj = 0; jj < 8; ++jj) s0[jj] = (f16)((na00[jj] + na10[jj]) * lh0);
                *(f16x8*)&As[b2][aoff] = s0;
                const f16 lh1 = (f16)RCP(nls1);
                f16x8 s1;
#pragma unroll
                for (int jj = 0; jj < 8; ++jj) s1[jj] = (f16)((na01[jj] + na11[jj]) * lh1);
                *(f16x8*)&As[b3][aoff] = s1;
            } else {
                GLD_LDS(ag + kb, &As[b2][wA]);
                GLD_LDS(ag + kb + 64, &As[b3][wA]);
            }
            GLD_LDS(bg + kb, &Bs[b2][wB]);
            GLD_LDS(bg + kb + 16 * rowK, &Bs[b2][wB + 16 * 32]);
            GLD_LDS(bg + kb + 64, &Bs[b3][wB]);
            GLD_LDS(bg + kb + 64 + 16 * rowK, &Bs[b3][wB + 16 * 32]);
        }
        // compute step k0 (buf b0) then k0+32 (buf b1) — no barrier between
        {
            f16x8 af[4], bf[NT];
#pragma unroll
            for (int mt = 0; mt < 4; ++mt)
                af[mt] = *(const f16x8*)&As[b0][(mt * 16 + fr) * 32 + sof];
#pragma unroll
            for (int nt = 0; nt < NT; ++nt)
                bf[nt] = *(const f16x8*)&Bs[b0][(wn + nt * 16 + fr) * 32 + sof];
#pragma unroll
            for (int mt = 0; mt < 4; ++mt)
#pragma unroll
                for (int nt = 0; nt < NT; ++nt)
                    acc[mt][nt] = __builtin_amdgcn_mfma_f32_16x16x32_f16(
                        af[mt], bf[nt], acc[mt][nt], 0, 0, 0);
        }
        {
            f16x8 af[4], bf[NT];
#pragma unroll
            for (int mt = 0; mt < 4; ++mt)
                af[mt] = *(const f16x8*)&As[b1][(mt * 16 + fr) * 32 + sof];
#pragma unroll
            for (int nt = 0; nt < NT; ++nt)
                bf[nt] = *(const f16x8*)&Bs[b1][(wn + nt * 16 + fr) * 32 + sof];
#pragma unroll
            for (int mt = 0; mt < 4; ++mt)
#pragma unroll
                for (int nt = 0; nt < NT; ++nt)
                    acc[mt][nt] = __builtin_amdgcn_mfma_f32_16x16x32_f16(
                        af[mt], bf[nt], acc[mt][nt], 0, 0, 0);
        }
    }

    // epilogue. C/D layout: col = lane&15, row = quad*4 + v
    float bvs[NT];
#pragma unroll
    for (int nt = 0; nt < NT; ++nt)
        bvs[nt] = (SPLITK == 2 && kk) ? 0.f : bias[col0 + wn + nt * 16 + fr];
    f16* outbase = (f16*)Cout + (SPLITK == 2 ? (size_t)kk * M * N : 0);
#pragma unroll
    for (int mt = 0; mt < 4; ++mt) {
        const int rowb = row0 + mt * 16 + quad * 4;
        float mv[4] = {1.f, 1.f, 1.f, 1.f};
        if (OUT_MODE == 2 && col0 >= 1536) {
            int4 mi = *(const int4*)&maskp[rowb];
            mv[0] = mi.x ? 1.f : 0.f; mv[1] = mi.y ? 1.f : 0.f;
            mv[2] = mi.z ? 1.f : 0.f; mv[3] = mi.w ? 1.f : 0.f;
        }
#pragma unroll
        for (int nt = 0; nt < NT; ++nt) {
            const int col = col0 + wn + nt * 16 + fr;
            if (OUT_MODE == 2) {
                const int bq = rowb >> 11, sb = rowb & 2047;
                if (col0 < 768) {                        // q -> Qout (scaled)
#pragma unroll
                    for (int v = 0; v < 4; ++v)
                        ((f16*)Cout)[(size_t)(rowb + v) * 768 + col]
                            = (f16)((acc[mt][nt][v] + bvs[nt]) * QSCALE);
                } else if (col0 < 1536) {                // k -> Kout tiles
                    const int dg = col - 768;
                    const int hh = dg >> 6, dd = dg & 63;
                    f16* kb = Kout + (size_t)(bq * NH + hh) * (TT * HD);
#pragma unroll
                    for (int v = 0; v < 4; ++v) {
                        const int s = sb + v;
                        kb[((s >> 4) * 128 + (dd >> 3) * 16 + (s & 15)) * 8 + (dd & 7)]
                            = (f16)(acc[mt][nt][v] + bvs[nt]);
                    }
                } else {                                 // v -> Vout tiles (masked)
                    const int dg = col - 1536;
                    const int hh = dg >> 6, dd = dg & 63;
                    f16* vb = Vout + (size_t)(bq * NH + hh) * (TT * HD);
                    f16x4 pk = {(f16)((acc[mt][nt][0] + bvs[nt]) * mv[0]),
                                (f16)((acc[mt][nt][1] + bvs[nt]) * mv[1]),
                                (f16)((acc[mt][nt][2] + bvs[nt]) * mv[2]),
                                (f16)((acc[mt][nt][3] + bvs[nt]) * mv[3])};
                    *(f16x4*)&vb[((sb >> 3) * 64 + dd) * 8 + (sb & 7)] = pk;
                }
            } else {
#pragma unroll
                for (int v = 0; v < 4; ++v) {
                    float o = acc[mt][nt][v] + bvs[nt];
                    if (GELU) o = gelu_f(o);
                    outbase[(size_t)(rowb + v) * N + col] = (f16)o;
                }
            }
        }
    }
}

// ---------------------------------------------------------------------------
// Barrier-free MFMA flash attention, key-range SPLIT (shalf in {0,1}).
// __launch_bounds__(256,3): verified R6 (-7us); R11 showed 4 regresses.
// s_setprio(1) around MFMA clusters (T5, verified R12: best total 265.9).
// Single-tile loop with unroll-2: R13 proved manual 2-deep ping-pong
// REGRESSES (compiler's unroll-2 already interleaves QK(t+1) with
// softmax(t); manual restructure added discarded work + register pressure).
// Softmax P redistribution fully in registers via cvt_pkrtz +
// permlane32/16_swap (verified R3: bank conflicts 2.75M->393K).
// ---------------------------------------------------------------------------
__global__ __launch_bounds__(256, 3)
void attn_mfma(const f16* __restrict__ qh, const f16* __restrict__ kth,
               const f16* __restrict__ vth, const int* __restrict__ mask,
               f16* __restrict__ O0, f16* __restrict__ O1,
               float* __restrict__ l0, float* __restrict__ l1)
{
    __shared__ __align__(16) char smem[16640];
    f16* Mf = (f16*)smem;                  // [2048] f16 mask row, 4KB
#if !HAVE_PERMLANE_SWAP
    f16* Ps = (f16*)(smem + 4096);         // [64][72] 9216B (fallback only)
#endif
    float* Ored  = (float*)smem;           // [64][64] f32 16KB (end only, overlays)
    float* lredp = (float*)(smem + 16384); // [64] f32

    const int id = blockIdx.x;
    const int xcd = id & 7, j = id >> 3;          // j in 0..191
    const int pair = xcd * 3 + j % 3;             // 0..23 = b*NH + h
    const int rem = j / 3;                        // 0..63
    const int qt = rem >> 1, shalf = rem & 1;
    const int b = pair / NH, h = pair % NH;

    const int t = threadIdx.x, lane = t & 63, w = t >> 6;
    const int wq = w >> 1, ws = w & 1;
    const int fr = lane & 15, quad = lane >> 4;

    // mask ints -> f16 row in LDS
    {
        int4 mi0 = *(const int4*)&mask[b * TT + t * 8];
        int4 mi1 = *(const int4*)&mask[b * TT + t * 8 + 4];
        f16x8 mrow;
        mrow[0] = mi0.x ? (f16)1.f : (f16)0.f; mrow[1] = mi0.y ? (f16)1.f : (f16)0.f;
        mrow[2] = mi0.z ? (f16)1.f : (f16)0.f; mrow[3] = mi0.w ? (f16)1.f : (f16)0.f;
        mrow[4] = mi1.x ? (f16)1.f : (f16)0.f; mrow[5] = mi1.y ? (f16)1.f : (f16)0.f;
        mrow[6] = mi1.z ? (f16)1.f : (f16)0.f; mrow[7] = mi1.w ? (f16)1.f : (f16)0.f;
        *(f16x8*)&Mf[t * 8] = mrow;
    }

    // Q B-frags direct from global: B[k=d][n=q], lane fr = q
    f16x8 qf[2][2];
#pragma unroll
    for (int nt = 0; nt < 2; ++nt)
#pragma unroll
        for (int ks = 0; ks < 2; ++ks)
            qf[nt][ks] = *(const f16x8*)&qh[(size_t)(b * TT + qt * 64 + wq * 32 + nt * 16 + fr) * CC
                                            + h * HD + ks * 32 + quad * 8];

    __syncthreads();   // Mf visible

    const f16* KB = kth + (size_t)(b * NH + h) * (TT * HD);
    const f16* VB = vth + (size_t)(b * NH + h) * (TT * HD);
    int ko[2][2], vo[4];
#pragma unroll
    for (int mt = 0; mt < 2; ++mt)
#pragma unroll
        for (int ks = 0; ks < 2; ++ks)
            ko[mt][ks] = ((ws * 2 + mt) * 128 + (ks * 4 + quad) * 16 + fr) * 8;
#pragma unroll
    for (int nt = 0; nt < 4; ++nt)
        vo[nt] = ((ws * 4 + quad) * 64 + nt * 16 + fr) * 8;

    f32x4 oacc[2][4] = {};
    f32x4 lacc[2] = {};

    const int it0 = shalf * 16;
#pragma unroll 2
    for (int it = it0; it < it0 + 16; ++it) {
        const int ib = it * 4096;
        f16x8 vf[4];
#pragma unroll
        for (int nt = 0; nt < 4; ++nt)
            vf[nt] = *(const f16x8*)(VB + ib + vo[nt]);
        f16x8 kf[2][2];
#pragma unroll
        for (int mt = 0; mt < 2; ++mt)
#pragma unroll
            for (int ks = 0; ks < 2; ++ks)
                kf[mt][ks] = *(const f16x8*)(KB + ib + ko[mt][ks]);

        // S^T = K · Q^T
        f32x4 sacc[2][2] = {};
        __builtin_amdgcn_s_setprio(1);
#pragma unroll
        for (int mt = 0; mt < 2; ++mt)
#pragma unroll
            for (int nt = 0; nt < 2; ++nt) {
                sacc[mt][nt] = __builtin_amdgcn_mfma_f32_16x16x32_f16(
                    kf[mt][0], qf[nt][0], sacc[mt][nt], 0, 0, 0);
                sacc[mt][nt] = __builtin_amdgcn_mfma_f32_16x16x32_f16(
                    kf[mt][1], qf[nt][1], sacc[mt][nt], 0, 0, 0);
            }
        __builtin_amdgcn_s_setprio(0);

        f16x8 mf = *(const f16x8*)&Mf[it * 64 + ws * 32 + quad * 8];

#if HAVE_PERMLANE_SWAP
        // in-register softmax + P redistribution
#pragma unroll
        for (int nt = 0; nt < 2; ++nt) {
            const u32 pa = pkrtz(EXP2(sacc[0][nt][0]), EXP2(sacc[0][nt][1]));
            const u32 pb = pkrtz(EXP2(sacc[0][nt][2]), EXP2(sacc[0][nt][3]));
            const u32 pc = pkrtz(EXP2(sacc[1][nt][0]), EXP2(sacc[1][nt][1]));
            const u32 pd = pkrtz(EXP2(sacc[1][nt][2]), EXP2(sacc[1][nt][3]));
            const u32x2 e0 = __builtin_amdgcn_permlane32_swap(pa, pc, false, false);
            const u32x2 e1 = __builtin_amdgcn_permlane16_swap(e0.x, e0.y, false, false);
            const u32x2 e2 = __builtin_amdgcn_permlane32_swap(pb, pd, false, false);
            const u32x2 e3 = __builtin_amdgcn_permlane16_swap(e2.x, e2.y, false, false);
            const u32x4 pw = {e1.x, e3.x, e1.y, e3.y};
            const f16x8 pfr = __builtin_bit_cast(f16x8, pw);
            __builtin_amdgcn_s_setprio(1);
            lacc[nt] = __builtin_amdgcn_mfma_f32_16x16x32_f16(pfr, mf, lacc[nt], 0, 0, 0);
#pragma unroll
            for (int vt = 0; vt < 4; ++vt)
                oacc[nt][vt] = __builtin_amdgcn_mfma_f32_16x16x32_f16(
                    pfr, vf[vt], oacc[nt][vt], 0, 0, 0);
            __builtin_amdgcn_s_setprio(0);
        }
#else
        // fallback: LDS round trip
#pragma unroll
        for (int mt = 0; mt < 2; ++mt)
#pragma unroll
            for (int nt = 0; nt < 2; ++nt) {
                f16x4 pk = {(f16)EXP2(sacc[mt][nt][0]), (f16)EXP2(sacc[mt][nt][1]),
                            (f16)EXP2(sacc[mt][nt][2]), (f16)EXP2(sacc[mt][nt][3])};
                *(f16x4*)&Ps[(wq * 32 + nt * 16 + fr) * 72 + ws * 32 + mt * 16 + quad * 4] = pk;
            }
        f16x8 pf[2];
#pragma unroll
        for (int mt = 0; mt < 2; ++mt)
            pf[mt] = *(const f16x8*)&Ps[(wq * 32 + mt * 16 + fr) * 72 + ws * 32 + quad * 8];
#pragma unroll
        for (int mt = 0; mt < 2; ++mt) {
            lacc[mt] = __builtin_amdgcn_mfma_f32_16x16x32_f16(pf[mt], mf, lacc[mt], 0, 0, 0);
#pragma unroll
            for (int nt = 0; nt < 4; ++nt)
                oacc[mt][nt] = __builtin_amdgcn_mfma_f32_16x16x32_f16(
                    pf[mt], vf[nt], oacc[mt][nt], 0, 0, 0);
        }
#endif
    }

    // cross-(ws) reduction; write unnormalized partials
    f16* Oout = shalf ? O1 : O0;
    float* lout = shalf ? l1 : l0;
    __syncthreads();
    if (ws == 1) {
#pragma unroll
        for (int mt = 0; mt < 2; ++mt) {
            const int q = wq * 32 + mt * 16 + quad * 4;
#pragma unroll
            for (int nt = 0; nt < 4; ++nt)
#pragma unroll
                for (int v = 0; v < 4; ++v)
                    Ored[(q + v) * 64 + nt * 16 + fr] = oacc[mt][nt][v];
            if (fr == 0)
#pragma unroll
                for (int v = 0; v < 4; ++v) lredp[q + v] = lacc[mt][v];
        }
    }
    __syncthreads();
    if (ws == 0) {
#pragma unroll
        for (int mt = 0; mt < 2; ++mt) {
            const int q0 = wq * 32 + mt * 16 + quad * 4;
            if (fr == 0)
#pragma unroll
                for (int v = 0; v < 4; ++v)
                    lout[(size_t)(b * TT + qt * 64 + q0 + v) * NH + h]
                        = lacc[mt][v] + lredp[q0 + v];
#pragma unroll
            for (int nt = 0; nt < 4; ++nt)
#pragma unroll
                for (int v = 0; v < 4; ++v) {
                    float o = oacc[mt][nt][v] + Ored[(q0 + v) * 64 + nt * 16 + fr];
                    Oout[(size_t)(b * TT + qt * 64 + q0 + v) * CC + h * HD + nt * 16 + fr]
                        = (f16)o;
                }
        }
    }
}

// ---------------------------------------------------------------------------
// out = res + LN(y0+y1)*gamma + beta, 8 rows/block, vectorized.
// ---------------------------------------------------------------------------
template<int WRITE_H>
__global__ __launch_bounds__(256)
void ln_residual(const float* __restrict__ res,
                 const f16* __restrict__ y0, const f16* __restrict__ y1,
                 const float* __restrict__ gamma, const float* __restrict__ beta,
                 float* __restrict__ outp, f16* __restrict__ outh)
{
    const int t = threadIdx.x;
    const int row = blockIdx.x * 8 + (t >> 5);
    const int c0 = (t & 31) * 24;
    const f16* yr0 = y0 + (size_t)row * CC + c0;
    const f16* yr1 = y1 + (size_t)row * CC + c0;
    float v[24];
    float s = 0.f, sq = 0.f;
#pragma unroll
    for (int i = 0; i < 3; ++i) {
        f16x8 a = *(const f16x8*)(yr0 + i * 8);
        f16x8 bb = *(const f16x8*)(yr1 + i * 8);
#pragma unroll
        for (int jj = 0; jj < 8; ++jj) {
            float vv = (float)a[jj] + (float)bb[jj];
            v[i * 8 + jj] = vv; s += vv; sq += vv * vv;
        }
    }
#pragma unroll
    for (int off = 1; off < 32; off <<= 1) {
        s  += __shfl_xor(s, off);
        sq += __shfl_xor(sq, off);
    }
    const float mean = s * (1.f / 768.f);
    const float var  = sq * (1.f / 768.f) - mean * mean;
    const float rstd = rsqrtf(var + 1e-5f);
    const float* rr = res + (size_t)row * CC + c0;
    float* orow = outp + (size_t)row * CC + c0;
#pragma unroll
    for (int i = 0; i < 6; ++i) {
        float4 r4 = *(const float4*)(rr + i * 4);
        float4 g4 = *(const float4*)(gamma + c0 + i * 4);
        float4 b4 = *(const float4*)(beta + c0 + i * 4);
        float4 o;
        o.x = r4.x + (v[i*4+0] - mean) * rstd * g4.x + b4.x;
        o.y = r4.y + (v[i*4+1] - mean) * rstd * g4.y + b4.y;
        o.z = r4.z + (v[i*4+2] - mean) * rstd * g4.z + b4.z;
        o.w = r4.w + (v[i*4+3] - mean) * rstd * g4.w + b4.w;
        *(float4*)(orow + i * 4) = o;
        if (WRITE_H) {
            f16x4 h4 = {(f16)o.x, (f16)o.y, (f16)o.z, (f16)o.w};
            *(f16x4*)(outh + (size_t)row * CC + c0 + i * 4) = h4;
        }
    }
}

// ---------------------------------------------------------------------------
extern "C" void kernel_launch(void* const* d_in, const int* in_sizes, int n_in,
                              void* d_out, int out_size, void* d_ws, size_t ws_size,
                              hipStream_t stream)
{
    const float* x     = (const float*)d_in[0];
    const int*   mask  = (const int*)  d_in[1];
    const float* Wqkv  = (const float*)d_in[2];
    const float* bqkv  = (const float*)d_in[3];
    const float* Wp    = (const float*)d_in[4];
    const float* bp    = (const float*)d_in[5];
    const float* g1    = (const float*)d_in[6];
    const float* be1   = (const float*)d_in[7];
    const float* W1    = (const float*)d_in[8];
    const float* b1    = (const float*)d_in[9];
    const float* W2    = (const float*)d_in[10];
    const float* b2    = (const float*)d_in[11];
    const float* g2    = (const float*)d_in[12];
    const float* be2   = (const float*)d_in[13];
    float* outp = (float*)d_out;

    // byte-offset workspace plan (~66.5 MB, overlays by lifetime):
    char* wsb = (char*)d_ws;
    f16*   qhb    = (f16*)(wsb);                 // 6.29MB   gemm1->attn
    f16*   kth    = (f16*)(wsb + 6291456);       // 6.29MB   gemm1->attn
    f16*   vth    = (f16*)(wsb + 12582912);      // 6.29MB   gemm1->attn
    f16*   O0     = (f16*)(wsb + 18874368);      // 6.29MB   attn->gemm3
    f16*   O1     = (f16*)(wsb + 25165824);      // 6.29MB   attn->gemm3 (over xh)
    f16*   hbuf   = (f16*)(wsb);                 // 25.17MB  gemm5->gemm6 (overlay)
    f16*   xh     = (f16*)(wsb + 25165824);      // 6.29MB   conv->gemm1 (then O1)
    float* out1f  = (float*)(wsb + 25165824);    // 12.58MB  ln1->ln2 (over O1/Wqkvt/Wpt)
    f16*   Wqkvt  = (f16*)(wsb + 31457280);      // 3.54MB   ->gemm1
    f16*   Wpt    = (f16*)(wsb + 34996224);      // 1.18MB   ->gemm3
    f16*   W1t    = (f16*)(wsb + 37748736);      // 4.72MB   ->gemm5
    f16*   W2t    = (f16*)(wsb + 42467328);      // 4.72MB   ->gemm6
    f16*   p0     = (f16*)(wsb + 47185920);      // 6.29MB   splitK partial 0
    f16*   p1     = (f16*)(wsb + 53477376);      // 6.29MB   splitK partial 1
    f16*   out1h  = (f16*)(wsb + 59768832);      // 6.29MB   ln1->gemm5
    float* l0     = (float*)(wsb + 66060288);    // 196KB    attn->gemm3
    float* l1     = (float*)(wsb + 66256896);    // 196KB    attn->gemm3; end 66.45MB

    const dim3 blk(256);

    // fused conversions (x + 4 weight transposes)
    conv_all<<<dim3(9984), blk, 0, stream>>>(x, xh, Wqkv, Wqkvt, Wp, Wpt,
                                             W1, W1t, W2, W2t);

    // 1. qkv = x @ Wqkv + bqkv -> qh (scaled) + kth/vth MFMA-tiled (v masked)
    //    48KB LDS -> 3 blocks/CU; MINW=3
    gemm_mfma<64, 2, 0, 1, 0, 3><<<dim3((3 * CC / 128) * (MM / 64)), blk, 0, stream>>>(
        xh, Wqkvt, bqkv, qhb, kth, vth, mask, MM, 3 * CC, CC,
        nullptr, nullptr, nullptr);
    // 2. attention -> unnormalized partials O0/O1 + l0/l1 (s-split, 1536 blocks)
    attn_mfma<<<dim3((TT / 64) * NH * BB * 2), blk, 0, stream>>>(
        qhb, kth, vth, mask, O0, O1, l0, l1);
    // 3. proj = [(O0+O1)/l] @ Wp + bp -> p0+p1 (split-K=2, combine in A-staging)
    gemm_mfma<64, 1, 0, 2, 1, 3><<<dim3(2 * (CC / 128) * (MM / 64)), blk, 0, stream>>>(
        O0, Wpt, bp, p0, nullptr, nullptr, nullptr, MM, CC, CC,
        O1, l0, l1);
    // 4. out1 = x + LN(p0+p1)  (fp32 + f16 copy)
    ln_residual<1><<<dim3(MM / 8), blk, 0, stream>>>(x, p0, p1, g1, be1, out1f, out1h);
    // 5. h = gelu(out1 @ W1 + b1) -> hbuf f16 (quad-buffer, 1 barrier/2 steps)
    gemm_mfma<64, 1, 1, 1, 0, 3><<<dim3((DFF / 128) * (MM / 64)), blk, 0, stream>>>(
        out1h, W1t, b1, hbuf, nullptr, nullptr, nullptr, MM, DFF, CC,
        nullptr, nullptr, nullptr);
    // 6. mlp = h @ W2 + b2 -> p0+p1 (split-K=2)
    gemm_mfma<64, 1, 0, 2, 0, 3><<<dim3(2 * (CC / 128) * (MM / 64)), blk, 0, stream>>>(
        hbuf, W2t, b2, p0, nullptr, nullptr, nullptr, MM, CC, DFF,
        nullptr, nullptr, nullptr);
    // 7. out = out1 + LN(p0+p1)
    ln_residual<0><<<dim3(MM / 8), blk, 0, stream>>>(out1f, p0, p1, g2, be2, outp, nullptr);
}